// Round 1
// baseline (9429.536 us; speedup 1.0000x reference)
//
#include <hip/hip_runtime.h>
#include <hip/hip_bf16.h>

#define BB 128
#define TT 128
#define HH 1024
#define NWG 256
#define NT 512

typedef __bf16 bf16x8 __attribute__((ext_vector_type(8)));
typedef __bf16 bf16x4 __attribute__((ext_vector_type(4)));
typedef float  f32x4v __attribute__((ext_vector_type(4)));

#define MFMA16(a,b,c) __builtin_amdgcn_mfma_f32_16x16x32_bf16(a,b,c,0,0,0)

__device__ inline float fsig(float x) {
  x = fminf(fmaxf(x, -30.f), 30.f);
  return 1.f / (1.f + __expf(-x));
}
__device__ inline float ftanh(float x) {
  x = fminf(fmaxf(x, -15.f), 15.f);
  float e = __expf(2.f * x);
  return (e - 1.f) / (e + 1.f);
}
__device__ inline float bf2f(unsigned short u) {
  union { unsigned int i; float f; } c; c.i = (unsigned int)u << 16; return c.f;
}
// UC (LLC coherent-point) 2B store for cross-WG state
__device__ inline void ucst16(__bf16* p, float v) {
  union { __bf16 b; unsigned short u; } c; c.b = (__bf16)v;
  __hip_atomic_store((unsigned short*)p, c.u, __ATOMIC_RELAXED, __HIP_MEMORY_SCOPE_AGENT);
}

// ---- per-wave DAG sync --------------------------------------------------------
// flags[role][rb][g]: rb = row-block (wave index, 8 blocks of 16 batch rows),
// g = producer column strip (64 strips of 16 cols). Every cross-WG dependency is
// row-block diagonal, so each wave runs its own independent 16-row chain with NO
// __syncthreads in the t-loop.

// wait on NSLOT contiguous slots (lane i polls slot i)
template<int NSLOT>
__device__ inline void wvwait(const int* P, int tgt, int lane) {
  if (lane < NSLOT) {
    while (__hip_atomic_load(&P[lane], __ATOMIC_RELAXED, __HIP_MEMORY_SCOPE_AGENT) < tgt)
      __builtin_amdgcn_s_sleep(1);
  }
  __builtin_amdgcn_fence(__ATOMIC_ACQUIRE, "agent");
  __builtin_amdgcn_sched_barrier(0);
}
// combined wait, one poll round: lanes 0..31 poll A[0..31] (a 32-slot column
// half), lanes 32..63 each poll a pair of B2[0..63] (full 64-slot set).
__device__ inline void wvwait_pair(const int* A, const int* B2, int tgt, int lane) {
  if (lane < 32) {
    const int* P = A + lane;
    while (__hip_atomic_load(P, __ATOMIC_RELAXED, __HIP_MEMORY_SCOPE_AGENT) < tgt)
      __builtin_amdgcn_s_sleep(1);
  } else {
    const int* P = B2 + (lane - 32) * 2;
    while (__hip_atomic_load(P,     __ATOMIC_RELAXED, __HIP_MEMORY_SCOPE_AGENT) < tgt ||
           __hip_atomic_load(P + 1, __ATOMIC_RELAXED, __HIP_MEMORY_SCOPE_AGENT) < tgt)
      __builtin_amdgcn_s_sleep(1);
  }
  __builtin_amdgcn_fence(__ATOMIC_ACQUIRE, "agent");
  __builtin_amdgcn_sched_barrier(0);
}
// per-wave signal: drain this wave's UC stores, then lane0 bumps the flag.
// (vmcnt(0)-before-flag is the same ordering mechanism the barriered version used.)
__device__ inline void wvsig(int* slot, int val, int lane) {
  asm volatile("s_waitcnt vmcnt(0)" ::: "memory");
  if (lane == 0)
    __hip_atomic_store(slot, val, __ATOMIC_RELAXED, __HIP_MEMORY_SCOPE_AGENT);
}

// ---- stage one 16x1024 f32 weight strip into LDS as swizzled bf16 (32KB), NT=512 ----
__device__ inline void stage_strip(char* dst, const float* src, int rstride, int tid) {
#pragma unroll
  for (int it = 0; it < 8; ++it) {
    int i = tid + it * NT;
    int rr = i >> 8;
    int c4 = i & 255;
    f32x4v v = *(const f32x4v*)(src + (size_t)rr * rstride + c4 * 4);
    bf16x4 o;
#pragma unroll
    for (int j = 0; j < 4; ++j) o[j] = (__bf16)v[j];
    *(bf16x4*)(dst + rr * 2048 + ((c4 * 8) ^ ((rr & 7) << 4))) = o;
  }
}

// ---- stage one 16x1024 bf16 strip into LDS swizzled (32KB), 256 threads ----
__device__ inline void stage_strip_b16(char* dst, const __bf16* src, int tid) {
#pragma unroll
  for (int it = 0; it < 8; ++it) {
    int i = tid + it * 256;
    int rr = i >> 7;
    int c8 = i & 127;
    bf16x8 v = *(const bf16x8*)(src + (size_t)rr * 1024 + c8 * 8);
    *(bf16x8*)(dst + rr * 2048 + ((c8 * 16) ^ ((rr & 7) << 4))) = v;
  }
}

// ---- half-K GEMM burst: 16 K-chunks (kb0..kb0+15), forced register burst ----
template<int NS>
__device__ inline void gemm_half(const char* sm, const __bf16* __restrict__ A,
                                 int rowbase, int lane, int kb0, f32x4v (&acc)[NS]) {
  const int r = lane & 15, q = lane >> 4;
  const __bf16* Ap = A + (size_t)(rowbase + r) * 1024 + q * 8;
  bf16x8 a[16];
#pragma unroll
  for (int i = 0; i < 16; ++i) a[i] = *(const bf16x8*)(Ap + (kb0 + i) * 32);
  __builtin_amdgcn_sched_barrier(0);   // pin: all 16 loads issued before MFMAs
  __builtin_amdgcn_s_setprio(1);
#pragma unroll
  for (int i = 0; i < 16; ++i) {
    const int kb = kb0 + i;
    const int byteo = (kb * 64 + q * 16) ^ ((r & 7) << 4);
#pragma unroll
    for (int s = 0; s < NS; ++s) {
      bf16x8 b = *(const bf16x8*)(sm + s * 32768 + r * 2048 + byteo);
      acc[s] = MFMA16(a[i], b, acc[s]);
    }
  }
  __builtin_amdgcn_s_setprio(0);
}

// ---- full-K GEMM burst (32 chunks) ----
template<int NS>
__device__ inline void gemm_burst(const char* sm, const __bf16* __restrict__ A,
                                  int rowbase, int lane, f32x4v (&acc)[NS]) {
  const int r = lane & 15, q = lane >> 4;
  const __bf16* Ap = A + (size_t)(rowbase + r) * 1024 + q * 8;
  bf16x8 a[32];
#pragma unroll
  for (int kb = 0; kb < 32; ++kb) a[kb] = *(const bf16x8*)(Ap + kb * 32);
  __builtin_amdgcn_sched_barrier(0);
  __builtin_amdgcn_s_setprio(1);
#pragma unroll
  for (int kb = 0; kb < 32; ++kb) {
    const int byteo = (kb * 64 + q * 16) ^ ((r & 7) << 4);
#pragma unroll
    for (int s = 0; s < NS; ++s) {
      bf16x8 b = *(const bf16x8*)(sm + s * 32768 + r * 2048 + byteo);
      acc[s] = MFMA16(a[kb], b, acc[s]);
    }
  }
  __builtin_amdgcn_s_setprio(0);
}

// ------------------------- persistent recurrent kernel -------------------------
// XCD-affine roles: xcd = wg&7, role = xcd>>1. All 8 waves GEMM (128 rows in one
// phase; batch-half stagger removed). Per-wave flags [role][rb][g]; the 8 row
// chains are fully independent — no __syncthreads after LDS init.
__global__ void __launch_bounds__(NT, 2) gru_persist(
    const float* __restrict__ Whh0, const float* __restrict__ Wih1,
    const float* __restrict__ Whh1, const float* __restrict__ Wlin,
    const __bf16* __restrict__ gi0b, const float* __restrict__ G,
    __bf16* __restrict__ h0b, __bf16* __restrict__ h1b,
    __bf16* __restrict__ h2b, __bf16* __restrict__ gh1b,
    float* __restrict__ out, int* flags)
{
  __shared__ char sm[106496];
  float* h2s = (float*)(sm + 98304);          // [128][16] f32, role 2 persistent
  const int tid = threadIdx.x, wg = blockIdx.x;
  const int wv = tid >> 6, lane = tid & 63;
  const int xcd = wg & 7;
  const int role = xcd >> 1;
  const int g = ((wg >> 3) << 1) | (xcd & 1); // 0..63
  const int c0 = g * 16;
  const int r = lane & 15, q = lane >> 4;
  const int rowbase = wv * 16;                // each wave owns 16 batch rows

  if (role == 0) {
    stage_strip(sm,         Whh0 + (size_t)c0 * 1024,          1024, tid);
    stage_strip(sm + 32768, Whh0 + (size_t)(1024 + c0) * 1024, 1024, tid);
    stage_strip(sm + 65536, Whh0 + (size_t)(2048 + c0) * 1024, 1024, tid);
  } else if (role == 1) {
    stage_strip(sm,         Whh1 + (size_t)c0 * 1024,          1024, tid);
    stage_strip(sm + 32768, Whh1 + (size_t)(1024 + c0) * 1024, 1024, tid);
    stage_strip(sm + 65536, Whh1 + (size_t)(2048 + c0) * 1024, 1024, tid);
  } else if (role == 2) {
    stage_strip(sm,         Wih1 + (size_t)c0 * 1024,          1024, tid);
    stage_strip(sm + 32768, Wih1 + (size_t)(1024 + c0) * 1024, 1024, tid);
    stage_strip(sm + 65536, Wih1 + (size_t)(2048 + c0) * 1024, 1024, tid);
    for (int i = tid; i < 2048; i += NT) {    // h2 f32 master <- G[1] slice
      int row = i >> 4, cc = i & 15;
      h2s[i] = G[131072 + row * 1024 + c0 + cc];
    }
  } else {
    stage_strip(sm,         Wlin + (size_t)c0 * 2048,        2048, tid); // linL
    stage_strip(sm + 32768, Wlin + (size_t)c0 * 2048 + 1024, 2048, tid); // linR
  }
  __syncthreads();   // only barrier: LDS weights + h2s visible to all waves

  // flag bases: flags[role*512 + rb*64 + g]
  int* F0 = flags;
  int* F1 = flags + 512;
  int* F2 = flags + 1024;
  int* F3 = flags + 1536;

  if (role == 0) {
    const int* Fw = F3 + wv * 64;
    int*       Fs = F0 + wv * 64 + g;
    for (int t = 0; t < TT; ++t) {
      __bf16* h1bP = h1b + (size_t)(t & 1) * 131072;   // parity buffer
      // gi0 scalars: flag-independent — issue before waits to hide LLC latency
      unsigned short pgr[4], pgz[4], pgn[4];
#pragma unroll
      for (int gg = 0; gg < 4; ++gg) {
        int row = rowbase + q * 4 + gg;
        const unsigned short* gp =
            (const unsigned short*)(gi0b + ((size_t)t * 128 + row) * 3072 + c0 + r);
        pgr[gg] = gp[0]; pgz[gg] = gp[1024]; pgn[gg] = gp[2048];
      }
      f32x4v acc[3];
#pragma unroll
      for (int s = 0; s < 3; ++s) { f32x4v z = {0,0,0,0}; acc[s] = z; }
      wvwait<32>(Fw, t, lane);                 // h0(t-1) cols 0..511, my rows
      gemm_half<3>(sm, h0b, rowbase, lane, 0, acc);
      wvwait<32>(Fw + 32, t, lane);            // cols 512..1023
      unsigned short ph[4];
#pragma unroll
      for (int gg = 0; gg < 4; ++gg)
        ph[gg] = *(const unsigned short*)(h0b + (size_t)(rowbase + q * 4 + gg) * 1024 + c0 + r);
      gemm_half<3>(sm, h0b, rowbase, lane, 16, acc);
#pragma unroll
      for (int gg = 0; gg < 4; ++gg) {
        int row = rowbase + q * 4 + gg;
        float rv = fsig(bf2f(pgr[gg]) + acc[0][gg]);
        float zv = fsig(bf2f(pgz[gg]) + acc[1][gg]);
        float nv = ftanh(bf2f(pgn[gg]) + rv * acc[2][gg]);
        ucst16(h1bP + (size_t)row * 1024 + c0 + r, (1.f - zv) * nv + zv * bf2f(ph[gg]));
      }
      wvsig(Fs, t + 1, lane);
    }
  } else if (role == 1) {
    const int* Fw = F2 + wv * 64;
    int*       Fs = F1 + wv * 64 + g;
    for (int t = 0; t < TT; ++t) {
      wvwait<64>(Fw, t, lane);                 // h2(t-1), my rows, all cols
      f32x4v acc[3];
#pragma unroll
      for (int s = 0; s < 3; ++s) { f32x4v z = {0,0,0,0}; acc[s] = z; }
      gemm_burst<3>(sm, h2b, rowbase, lane, acc);
#pragma unroll
      for (int gg = 0; gg < 4; ++gg) {
        size_t base = (size_t)(rowbase + q * 4 + gg) * 3072 + c0 + r;
        ucst16(gh1b + base,        acc[0][gg]);
        ucst16(gh1b + base + 1024, acc[1][gg]);
        ucst16(gh1b + base + 2048, acc[2][gg]);
      }
      wvsig(Fs, t + 1, lane);
    }
  } else if (role == 2) {
    const int* FwA = F1 + wv * 64 + g;   // gh1b strip: ONE producer (WG g, wave rb)
    const int* FwB = F0 + wv * 64;       // h1(t): all 64 col strips, my rows
    const int* FwC = F1 + wv * 64;       // WAR guard: all role1 consumed h2(t-1)
    int*       Fs  = F2 + wv * 64 + g;
    for (int t = 0; t < TT; ++t) {
      const __bf16* h1bP = h1b + (size_t)(t & 1) * 131072;
      wvwait<1>(FwA, t + 1, lane);
      unsigned short hg0[4], hg1[4], hg2[4];
#pragma unroll
      for (int gg = 0; gg < 4; ++gg) {
        const unsigned short* hp =
            (const unsigned short*)(gh1b + (size_t)(rowbase + q * 4 + gg) * 3072 + c0 + r);
        hg0[gg] = hp[0]; hg1[gg] = hp[1024]; hg2[gg] = hp[2048];
      }
      f32x4v acc[3];
#pragma unroll
      for (int s = 0; s < 3; ++s) { f32x4v z = {0,0,0,0}; acc[s] = z; }
      wvwait<32>(FwB, t + 1, lane);
      gemm_half<3>(sm, h1bP, rowbase, lane, 0, acc);
      // one round: h1 cols 512..1023 ready AND all-64 WAR guard (normally idle)
      wvwait_pair(FwB + 32, FwC, t + 1, lane);
      gemm_half<3>(sm, h1bP, rowbase, lane, 16, acc);
#pragma unroll
      for (int gg = 0; gg < 4; ++gg) {
        int row = rowbase + q * 4 + gg;
        float rv = fsig(acc[0][gg] + bf2f(hg0[gg]));
        float zv = fsig(acc[1][gg] + bf2f(hg1[gg]));
        float nv = ftanh(acc[2][gg] + rv * bf2f(hg2[gg]));
        float hp = h2s[row * 16 + r];
        float h2 = (1.f - zv) * nv + zv * hp;
        h2s[row * 16 + r] = h2;
        ucst16(h2b + (size_t)row * 1024 + c0 + r, h2);
      }
      wvsig(Fs, t + 1, lane);
    }
  } else {
    const int* FwOwn = F3 + wv * 64;     // h0(t-1) fully written, my rows
    const int* FwC   = F2 + wv * 64;     // h2(t), column halves
    int*       Fs    = F3 + wv * 64 + g;
    for (int t = 0; t < TT; ++t) {
      wvwait<64>(FwOwn, t, lane);
      f32x4v accL[1];
      { f32x4v z = {0,0,0,0}; accL[0] = z; }
      gemm_burst<1>(sm, h0b, rowbase, lane, accL);
      f32x4v accR[1];
      { f32x4v z = {0,0,0,0}; accR[0] = z; }
      wvwait<32>(FwC, t + 1, lane);
      gemm_half<1>(sm + 32768, h2b, rowbase, lane, 0, accR);
      wvwait<32>(FwC + 32, t + 1, lane);
      gemm_half<1>(sm + 32768, h2b, rowbase, lane, 16, accR);
#pragma unroll
      for (int gg = 0; gg < 4; ++gg) {
        int row = rowbase + q * 4 + gg;
        float v = ftanh(accL[0][gg] + accR[0][gg]);
        ucst16(h0b + (size_t)row * 1024 + c0 + r, v);
        out[((size_t)row * 128 + t) * 1024 + c0 + r] = v;
      }
      wvsig(Fs, t + 1, lane);
    }
  }
}

// ------------------------- gi0 precompute -> gi0b[t][b][3H] bf16 -------------------------
__global__ void __launch_bounds__(256) gi0_kernel(const float* __restrict__ X,
                                                  const __bf16* __restrict__ Wih0b,
                                                  __bf16* __restrict__ gi0b) {
  __shared__ char sm[131072];
  const int tid = threadIdx.x, wv = tid >> 6, lane = tid & 63;
  const int bi = blockIdx.x;
  const int n = bi % 48, mg = bi / 48;
#pragma unroll
  for (int s = 0; s < 4; ++s)
    stage_strip_b16(sm + s * 32768, Wih0b + (size_t)(n * 64 + s * 16) * 1024, tid);
  __syncthreads();
  const int r = lane & 15, q = lane >> 4;
  for (int mi = mg * 4; mi < mg * 4 + 4; ++mi) {
    f32x4v acc[4][2];
#pragma unroll
    for (int s = 0; s < 4; ++s) { f32x4v z = {0,0,0,0}; acc[s][0] = z; acc[s][1] = z; }
    const float* Ap = X + ((size_t)mi * 128 + wv * 32 + r) * 1024 + q * 8;
#pragma unroll 4
    for (int kb = 0; kb < 32; ++kb) {
      f32x4v x0a = *(const f32x4v*)(Ap + kb * 32);
      f32x4v x0b = *(const f32x4v*)(Ap + kb * 32 + 4);
      f32x4v x1a = *(const f32x4v*)(Ap + 16384 + kb * 32);
      f32x4v x1b = *(const f32x4v*)(Ap + 16384 + kb * 32 + 4);
      bf16x8 a0, a1;
#pragma unroll
      for (int j = 0; j < 4; ++j) {
        a0[j] = (__bf16)x0a[j]; a0[4 + j] = (__bf16)x0b[j];
        a1[j] = (__bf16)x1a[j]; a1[4 + j] = (__bf16)x1b[j];
      }
      const int byteo = (kb * 64 + q * 16) ^ ((r & 7) << 4);
#pragma unroll
      for (int s = 0; s < 4; ++s) {
        bf16x8 b = *(const bf16x8*)(sm + s * 32768 + r * 2048 + byteo);
        acc[s][0] = MFMA16(a0, b, acc[s][0]);
        acc[s][1] = MFMA16(a1, b, acc[s][1]);
      }
    }
#pragma unroll
    for (int s = 0; s < 4; ++s)
#pragma unroll
      for (int mf = 0; mf < 2; ++mf)
#pragma unroll
        for (int gg = 0; gg < 4; ++gg) {
          int trow = wv * 32 + mf * 16 + q * 4 + gg;     // = t
          gi0b[((size_t)trow * 128 + mi) * 3072 + n * 64 + s * 16 + r] = (__bf16)acc[s][mf][gg];
        }
  }
}

// ------------------------- prep: Wih0->bf16, state init, flags -------------------------
__global__ void __launch_bounds__(256) prep3(const float* __restrict__ Wih0f,
                                             const float* __restrict__ G,
                                             __bf16* Wih0b,
                                             __bf16* h0b, __bf16* h2b, int* flags) {
  long c = (long)blockIdx.x * 256 + threadIdx.x;
  if (c < 786432) {
    f32x4v v = *(const f32x4v*)(Wih0f + c * 4);
    bf16x4 o;
#pragma unroll
    for (int j = 0; j < 4; ++j) o[j] = (__bf16)v[j];
    *(bf16x4*)(Wih0b + c * 4) = o;
  } else if (c < 786432 + 131072) {
    long i = c - 786432;
    h0b[i] = (__bf16)G[i];
  } else if (c < 786432 + 262144) {
    long i = c - 786432 - 131072;
    h2b[i] = (__bf16)G[131072 + i];
  } else if (c < 786432 + 262144 + 2048) {
    flags[c - 786432 - 262144] = 0;
  }
}

// ------------------------- final LayerNorm (ddof=1, denom std+eps) -------------------------
__global__ void __launch_bounds__(256) ln_kernel(float* __restrict__ out,
                                                 const float* __restrict__ a2,
                                                 const float* __restrict__ b2) {
  int wv = threadIdx.x >> 6, lane = threadIdx.x & 63;
  size_t row = (size_t)blockIdx.x * 4 + wv;
  float* p = out + row * 1024;
  f32x4v v[4];
  float s = 0.f, ss = 0.f;
#pragma unroll
  for (int i = 0; i < 4; ++i) {
    v[i] = *(const f32x4v*)(p + (i * 64 + lane) * 4);
#pragma unroll
    for (int j = 0; j < 4; ++j) { s += v[i][j]; ss += v[i][j] * v[i][j]; }
  }
#pragma unroll
  for (int o = 32; o > 0; o >>= 1) { s += __shfl_xor(s, o); ss += __shfl_xor(ss, o); }
  float mean = s * (1.f / 1024.f);
  float var = (ss - 1024.f * mean * mean) * (1.f / 1023.f);
  var = fmaxf(var, 0.f);
  float inv = 1.f / (sqrtf(var) + 1e-6f);
#pragma unroll
  for (int i = 0; i < 4; ++i) {
    int c0 = (i * 64 + lane) * 4;
    f32x4v gA = *(const f32x4v*)(a2 + c0);
    f32x4v bo = *(const f32x4v*)(b2 + c0);
    f32x4v o;
#pragma unroll
    for (int j = 0; j < 4; ++j) o[j] = gA[j] * (v[i][j] - mean) * inv + bo[j];
    *(f32x4v*)(p + c0) = o;
  }
}

extern "C" void kernel_launch(void* const* d_in, const int* in_sizes, int n_in,
                              void* d_out, int out_size, void* d_ws, size_t ws_size,
                              hipStream_t stream) {
  const float* X    = (const float*)d_in[0];
  const float* G    = (const float*)d_in[1];
  // d_in[2] = L : dead (attention result discarded in reference)
  const float* Wih0 = (const float*)d_in[3];
  const float* Whh0 = (const float*)d_in[4];
  const float* Wih1 = (const float*)d_in[5];
  const float* Whh1 = (const float*)d_in[6];
  const float* Wlin = (const float*)d_in[7];
  const float* a2   = (const float*)d_in[8];
  const float* b2   = (const float*)d_in[9];
  float* out = (float*)d_out;

  char* ws = (char*)d_ws;
  size_t off = 0;
  auto take = [&](size_t n) { char* p = ws + off; off += (n + 255) & ~(size_t)255; return p; };
  __bf16* Wih0b = (__bf16*)take((size_t)3072 * 1024 * 2);
  __bf16* gi0b  = (__bf16*)take((size_t)16384 * 3072 * 2);   // 96 MB, [t][b][3H]
  __bf16* gh1b  = (__bf16*)take((size_t)128 * 3072 * 2);
  __bf16* h0b   = (__bf16*)take((size_t)BB * HH * 2);
  __bf16* h1b   = (__bf16*)take((size_t)BB * HH * 2 * 2);    // parity double buffer
  __bf16* h2b   = (__bf16*)take((size_t)BB * HH * 2);
  int*    flags = (int*)take(2048 * 4);                      // [role][rb][g]
  if (off > ws_size) return; // workspace too small: fail loudly (output stays poisoned)

  prep3<<<4104, 256, 0, stream>>>(Wih0, G, Wih0b, h0b, h2b, flags);
  gi0_kernel<<<1536, 256, 0, stream>>>(X, Wih0b, gi0b);
  gru_persist<<<NWG, NT, 0, stream>>>(Whh0, Wih1, Whh1, Wlin, gi0b, G,
                                      h0b, h1b, h2b, gh1b, out, flags);
  ln_kernel<<<4096, 256, 0, stream>>>(out, a2, b2);
}

// Round 2
// 5706.716 us; speedup vs baseline: 1.6524x; 1.6524x over previous
//
#include <hip/hip_runtime.h>
#include <hip/hip_bf16.h>

#define BB 128
#define TT 128
#define HH 1024
#define NWG 256
#define NT 512

typedef __bf16 bf16x8 __attribute__((ext_vector_type(8)));
typedef __bf16 bf16x4 __attribute__((ext_vector_type(4)));
typedef float  f32x4v __attribute__((ext_vector_type(4)));

#define MFMA16(a,b,c) __builtin_amdgcn_mfma_f32_16x16x32_bf16(a,b,c,0,0,0)

__device__ inline float fsig(float x) {
  x = fminf(fmaxf(x, -30.f), 30.f);
  return 1.f / (1.f + __expf(-x));
}
__device__ inline float ftanh(float x) {
  x = fminf(fmaxf(x, -15.f), 15.f);
  float e = __expf(2.f * x);
  return (e - 1.f) / (e + 1.f);
}
__device__ inline float bf2f(unsigned short u) {
  union { unsigned int i; float f; } c; c.i = (unsigned int)u << 16; return c.f;
}
// UC (LLC coherent-point) 2B store for cross-WG state
__device__ inline void ucst16(__bf16* p, float v) {
  union { __bf16 b; unsigned short u; } c; c.b = (__bf16)v;
  __hip_atomic_store((unsigned short*)p, c.u, __ATOMIC_RELAXED, __HIP_MEMORY_SCOPE_AGENT);
}

// ---- DAG sync: WG-level 64-slot flag arrays, one per role (batch halves merged).
// Slot g: producer WG for columns g*16..g*16+15. Strips 0..31 = cols 0..511
// (column half 0), strips 32..63 = cols 512..1023 (column half 1).
// Mechanism (proven in r0): one polling wave (tid<64) + __syncthreads broadcast;
// signal = __syncthreads (compiler drains vmcnt before s_barrier) + tid0 store.
#define SIGF(F) do { \
  __syncthreads(); \
  if (tid == 0) \
    __hip_atomic_store(&(F)[g], t + 1, __ATOMIC_RELAXED, __HIP_MEMORY_SCOPE_AGENT); \
} while (0)

// full wait: all 64 slots
__device__ inline void wf1(const int* F, int tgt, int tid, int lane) {
  if (tid < 64) {
    while (__hip_atomic_load(&F[lane], __ATOMIC_RELAXED, __HIP_MEMORY_SCOPE_AGENT) < tgt)
      __builtin_amdgcn_s_sleep(1);
    __builtin_amdgcn_fence(__ATOMIC_ACQUIRE, "agent");
  }
  __syncthreads();
  __builtin_amdgcn_sched_barrier(0);
}
// half wait: 32 slots of one column half
__device__ inline void whalf(const int* F, int ch, int tgt, int tid, int lane) {
  if (tid < 64) {
    const int* P = F + ch * 32 + (lane & 31);
    while (__hip_atomic_load(P, __ATOMIC_RELAXED, __HIP_MEMORY_SCOPE_AGENT) < tgt)
      __builtin_amdgcn_s_sleep(1);
    __builtin_amdgcn_fence(__ATOMIC_ACQUIRE, "agent");
  }
  __syncthreads();
  __builtin_amdgcn_sched_barrier(0);
}

// ---- stage one 16x1024 f32 weight strip into LDS as swizzled bf16 (32KB), NT=512 ----
__device__ inline void stage_strip(char* dst, const float* src, int rstride, int tid) {
#pragma unroll
  for (int it = 0; it < 8; ++it) {
    int i = tid + it * NT;
    int rr = i >> 8;
    int c4 = i & 255;
    f32x4v v = *(const f32x4v*)(src + (size_t)rr * rstride + c4 * 4);
    bf16x4 o;
#pragma unroll
    for (int j = 0; j < 4; ++j) o[j] = (__bf16)v[j];
    *(bf16x4*)(dst + rr * 2048 + ((c4 * 8) ^ ((rr & 7) << 4))) = o;
  }
}

// ---- stage one 16x1024 bf16 strip into LDS swizzled (32KB), 256 threads ----
__device__ inline void stage_strip_b16(char* dst, const __bf16* src, int tid) {
#pragma unroll
  for (int it = 0; it < 8; ++it) {
    int i = tid + it * 256;
    int rr = i >> 7;
    int c8 = i & 127;
    bf16x8 v = *(const bf16x8*)(src + (size_t)rr * 1024 + c8 * 8);
    *(bf16x8*)(dst + rr * 2048 + ((c8 * 16) ^ ((rr & 7) << 4))) = v;
  }
}

// ---- half-K GEMM burst: 16 K-chunks (kb0..kb0+15), forced register burst ----
template<int NS>
__device__ inline void gemm_half(const char* sm, const __bf16* __restrict__ A,
                                 int rowbase, int lane, int kb0, f32x4v (&acc)[NS]) {
  const int r = lane & 15, q = lane >> 4;
  const __bf16* Ap = A + (size_t)(rowbase + r) * 1024 + q * 8;
  bf16x8 a[16];
#pragma unroll
  for (int i = 0; i < 16; ++i) a[i] = *(const bf16x8*)(Ap + (kb0 + i) * 32);
  __builtin_amdgcn_sched_barrier(0);   // pin: all 16 loads issued before MFMAs
  __builtin_amdgcn_s_setprio(1);
#pragma unroll
  for (int i = 0; i < 16; ++i) {
    const int kb = kb0 + i;
    const int byteo = (kb * 64 + q * 16) ^ ((r & 7) << 4);
#pragma unroll
    for (int s = 0; s < NS; ++s) {
      bf16x8 b = *(const bf16x8*)(sm + s * 32768 + r * 2048 + byteo);
      acc[s] = MFMA16(a[i], b, acc[s]);
    }
  }
  __builtin_amdgcn_s_setprio(0);
}

// ---- full-K GEMM burst (32 chunks) ----
template<int NS>
__device__ inline void gemm_burst(const char* sm, const __bf16* __restrict__ A,
                                  int rowbase, int lane, f32x4v (&acc)[NS]) {
  const int r = lane & 15, q = lane >> 4;
  const __bf16* Ap = A + (size_t)(rowbase + r) * 1024 + q * 8;
  bf16x8 a[32];
#pragma unroll
  for (int kb = 0; kb < 32; ++kb) a[kb] = *(const bf16x8*)(Ap + kb * 32);
  __builtin_amdgcn_sched_barrier(0);
  __builtin_amdgcn_s_setprio(1);
#pragma unroll
  for (int kb = 0; kb < 32; ++kb) {
    const int byteo = (kb * 64 + q * 16) ^ ((r & 7) << 4);
#pragma unroll
    for (int s = 0; s < NS; ++s) {
      bf16x8 b = *(const bf16x8*)(sm + s * 32768 + r * 2048 + byteo);
      acc[s] = MFMA16(a[kb], b, acc[s]);
    }
  }
  __builtin_amdgcn_s_setprio(0);
}

// ------------------------- persistent recurrent kernel -------------------------
// XCD-affine roles: xcd = wg&7, role = xcd>>1. Batch halves MERGED: all 8 waves
// GEMM (128 rows in one phase per role per step) — critical cycle is 3 phases
// (role0 -> role2 -> role3) instead of r0's 6 half-phases. Sync mechanism is
// r0's proven WG-level one (single polling wave + syncthreads + barriered SIGF).
__global__ void __launch_bounds__(NT, 2) gru_persist(
    const float* __restrict__ Whh0, const float* __restrict__ Wih1,
    const float* __restrict__ Whh1, const float* __restrict__ Wlin,
    const __bf16* __restrict__ gi0b, const float* __restrict__ G,
    __bf16* __restrict__ h0b, __bf16* __restrict__ h1b,
    __bf16* __restrict__ h2b, __bf16* __restrict__ gh1b,
    float* __restrict__ out, int* flags)
{
  __shared__ char sm[106496];
  float* h2s = (float*)(sm + 98304);          // [128][16] f32, role 2 persistent
  const int tid = threadIdx.x, wg = blockIdx.x;
  const int wv = tid >> 6, lane = tid & 63;
  const int xcd = wg & 7;
  const int role = xcd >> 1;
  const int g = ((wg >> 3) << 1) | (xcd & 1); // 0..63
  const int c0 = g * 16;
  const int r = lane & 15, q = lane >> 4;
  const int rowbase = wv * 16;                // each wave owns 16 batch rows

  if (role == 0) {
    stage_strip(sm,         Whh0 + (size_t)c0 * 1024,          1024, tid);
    stage_strip(sm + 32768, Whh0 + (size_t)(1024 + c0) * 1024, 1024, tid);
    stage_strip(sm + 65536, Whh0 + (size_t)(2048 + c0) * 1024, 1024, tid);
  } else if (role == 1) {
    stage_strip(sm,         Whh1 + (size_t)c0 * 1024,          1024, tid);
    stage_strip(sm + 32768, Whh1 + (size_t)(1024 + c0) * 1024, 1024, tid);
    stage_strip(sm + 65536, Whh1 + (size_t)(2048 + c0) * 1024, 1024, tid);
  } else if (role == 2) {
    stage_strip(sm,         Wih1 + (size_t)c0 * 1024,          1024, tid);
    stage_strip(sm + 32768, Wih1 + (size_t)(1024 + c0) * 1024, 1024, tid);
    stage_strip(sm + 65536, Wih1 + (size_t)(2048 + c0) * 1024, 1024, tid);
    for (int i = tid; i < 2048; i += NT) {    // h2 f32 master <- G[1] slice (all rows)
      int row = i >> 4, cc = i & 15;
      h2s[i] = G[131072 + row * 1024 + c0 + cc];
    }
  } else {
    stage_strip(sm,         Wlin + (size_t)c0 * 2048,        2048, tid); // linL
    stage_strip(sm + 32768, Wlin + (size_t)c0 * 2048 + 1024, 2048, tid); // linR
  }
  __syncthreads();

  // flag bases: F(role) = flags + role*64
  int* F0 = flags;
  int* F1 = flags + 64;
  int* F2 = flags + 128;
  int* F3 = flags + 192;

  if (role == 0) {
    for (int t = 0; t < TT; ++t) {
      __bf16* h1bP = h1b + (size_t)(t & 1) * 131072;   // parity buffer
      // gi0 scalars: flag-independent — issue before waits to hide LLC latency
      unsigned short pgr[4], pgz[4], pgn[4];
#pragma unroll
      for (int gg = 0; gg < 4; ++gg) {
        int row = rowbase + q * 4 + gg;
        const unsigned short* gp =
            (const unsigned short*)(gi0b + ((size_t)t * 128 + row) * 3072 + c0 + r);
        pgr[gg] = gp[0]; pgz[gg] = gp[1024]; pgn[gg] = gp[2048];
      }
      f32x4v acc[3];
#pragma unroll
      for (int s = 0; s < 3; ++s) { f32x4v z = {0,0,0,0}; acc[s] = z; }
      whalf(F3, 0, t, tid, lane);              // h0(t-1) cols 0..511 ready
      gemm_half<3>(sm, h0b, rowbase, lane, 0, acc);
      whalf(F3, 1, t, tid, lane);              // cols 512..1023 ready
      unsigned short ph[4];
#pragma unroll
      for (int gg = 0; gg < 4; ++gg)
        ph[gg] = *(const unsigned short*)(h0b + (size_t)(rowbase + q * 4 + gg) * 1024 + c0 + r);
      gemm_half<3>(sm, h0b, rowbase, lane, 16, acc);
#pragma unroll
      for (int gg = 0; gg < 4; ++gg) {
        int row = rowbase + q * 4 + gg;
        float rv = fsig(bf2f(pgr[gg]) + acc[0][gg]);
        float zv = fsig(bf2f(pgz[gg]) + acc[1][gg]);
        float nv = ftanh(bf2f(pgn[gg]) + rv * acc[2][gg]);
        ucst16(h1bP + (size_t)row * 1024 + c0 + r, (1.f - zv) * nv + zv * bf2f(ph[gg]));
      }
      SIGF(F0);
    }
  } else if (role == 1) {
    for (int t = 0; t < TT; ++t) {
      wf1(F2, t, tid, lane);                   // h2(t-1) ready (also gh1b WAR guard)
      f32x4v acc[3];
#pragma unroll
      for (int s = 0; s < 3; ++s) { f32x4v z = {0,0,0,0}; acc[s] = z; }
      gemm_burst<3>(sm, h2b, rowbase, lane, acc);
#pragma unroll
      for (int gg = 0; gg < 4; ++gg) {
        size_t base = (size_t)(rowbase + q * 4 + gg) * 3072 + c0 + r;
        ucst16(gh1b + base,        acc[0][gg]);
        ucst16(gh1b + base + 1024, acc[1][gg]);
        ucst16(gh1b + base + 2048, acc[2][gg]);
      }
      SIGF(F1);
    }
  } else if (role == 2) {
    for (int t = 0; t < TT; ++t) {
      const __bf16* h1bP = h1b + (size_t)(t & 1) * 131072;
      // stage A: gh1(t) ready (runs parallel with role0) + WAR guard on h2b.
      wf1(F1, t + 1, tid, lane);
      unsigned short hg0[4], hg1[4], hg2[4];
#pragma unroll
      for (int gg = 0; gg < 4; ++gg) {
        const unsigned short* hp =
            (const unsigned short*)(gh1b + (size_t)(rowbase + q * 4 + gg) * 3072 + c0 + r);
        hg0[gg] = hp[0]; hg1[gg] = hp[1024]; hg2[gg] = hp[2048];
      }
      // stage B: h1(t) in column halves
      f32x4v acc[3];
#pragma unroll
      for (int s = 0; s < 3; ++s) { f32x4v z = {0,0,0,0}; acc[s] = z; }
      whalf(F0, 0, t + 1, tid, lane);
      gemm_half<3>(sm, h1bP, rowbase, lane, 0, acc);
      whalf(F0, 1, t + 1, tid, lane);
      gemm_half<3>(sm, h1bP, rowbase, lane, 16, acc);
#pragma unroll
      for (int gg = 0; gg < 4; ++gg) {
        int row = rowbase + q * 4 + gg;
        float rv = fsig(acc[0][gg] + bf2f(hg0[gg]));
        float zv = fsig(acc[1][gg] + bf2f(hg1[gg]));
        float nv = ftanh(acc[2][gg] + rv * bf2f(hg2[gg]));
        float hp = h2s[row * 16 + r];
        float h2 = (1.f - zv) * nv + zv * hp;
        h2s[row * 16 + r] = h2;
        ucst16(h2b + (size_t)row * 1024 + c0 + r, h2);
      }
      SIGF(F2);
    }
  } else {
    for (int t = 0; t < TT; ++t) {
      wf1(F3, t, tid, lane);                   // own-role: h0(t-1) fully written
      f32x4v accL[1];
      { f32x4v z = {0,0,0,0}; accL[0] = z; }
      gemm_burst<1>(sm, h0b, rowbase, lane, accL);
      // linR in column halves as h2(t) arrives
      f32x4v accR[1];
      { f32x4v z = {0,0,0,0}; accR[0] = z; }
      whalf(F2, 0, t + 1, tid, lane);
      gemm_half<1>(sm + 32768, h2b, rowbase, lane, 0, accR);
      whalf(F2, 1, t + 1, tid, lane);
      gemm_half<1>(sm + 32768, h2b, rowbase, lane, 16, accR);
#pragma unroll
      for (int gg = 0; gg < 4; ++gg) {
        int row = rowbase + q * 4 + gg;
        float v = ftanh(accL[0][gg] + accR[0][gg]);
        ucst16(h0b + (size_t)row * 1024 + c0 + r, v);
        out[((size_t)row * 128 + t) * 1024 + c0 + r] = v;
      }
      SIGF(F3);
    }
  }
}

// ------------------------- gi0 precompute -> gi0b[t][b][3H] bf16 -------------------------
__global__ void __launch_bounds__(256) gi0_kernel(const float* __restrict__ X,
                                                  const __bf16* __restrict__ Wih0b,
                                                  __bf16* __restrict__ gi0b) {
  __shared__ char sm[131072];
  const int tid = threadIdx.x, wv = tid >> 6, lane = tid & 63;
  const int bi = blockIdx.x;
  const int n = bi % 48, mg = bi / 48;
#pragma unroll
  for (int s = 0; s < 4; ++s)
    stage_strip_b16(sm + s * 32768, Wih0b + (size_t)(n * 64 + s * 16) * 1024, tid);
  __syncthreads();
  const int r = lane & 15, q = lane >> 4;
  for (int mi = mg * 4; mi < mg * 4 + 4; ++mi) {
    f32x4v acc[4][2];
#pragma unroll
    for (int s = 0; s < 4; ++s) { f32x4v z = {0,0,0,0}; acc[s][0] = z; acc[s][1] = z; }
    const float* Ap = X + ((size_t)mi * 128 + wv * 32 + r) * 1024 + q * 8;
#pragma unroll 4
    for (int kb = 0; kb < 32; ++kb) {
      f32x4v x0a = *(const f32x4v*)(Ap + kb * 32);
      f32x4v x0b = *(const f32x4v*)(Ap + kb * 32 + 4);
      f32x4v x1a = *(const f32x4v*)(Ap + 16384 + kb * 32);
      f32x4v x1b = *(const f32x4v*)(Ap + 16384 + kb * 32 + 4);
      bf16x8 a0, a1;
#pragma unroll
      for (int j = 0; j < 4; ++j) {
        a0[j] = (__bf16)x0a[j]; a0[4 + j] = (__bf16)x0b[j];
        a1[j] = (__bf16)x1a[j]; a1[4 + j] = (__bf16)x1b[j];
      }
      const int byteo = (kb * 64 + q * 16) ^ ((r & 7) << 4);
#pragma unroll
      for (int s = 0; s < 4; ++s) {
        bf16x8 b = *(const bf16x8*)(sm + s * 32768 + r * 2048 + byteo);
        acc[s][0] = MFMA16(a0, b, acc[s][0]);
        acc[s][1] = MFMA16(a1, b, acc[s][1]);
      }
    }
#pragma unroll
    for (int s = 0; s < 4; ++s)
#pragma unroll
      for (int mf = 0; mf < 2; ++mf)
#pragma unroll
        for (int gg = 0; gg < 4; ++gg) {
          int trow = wv * 32 + mf * 16 + q * 4 + gg;     // = t
          gi0b[((size_t)trow * 128 + mi) * 3072 + n * 64 + s * 16 + r] = (__bf16)acc[s][mf][gg];
        }
  }
}

// ------------------------- prep: Wih0->bf16, state init, flags -------------------------
__global__ void __launch_bounds__(256) prep3(const float* __restrict__ Wih0f,
                                             const float* __restrict__ G,
                                             __bf16* Wih0b,
                                             __bf16* h0b, __bf16* h2b, int* flags) {
  long c = (long)blockIdx.x * 256 + threadIdx.x;
  if (c < 786432) {
    f32x4v v = *(const f32x4v*)(Wih0f + c * 4);
    bf16x4 o;
#pragma unroll
    for (int j = 0; j < 4; ++j) o[j] = (__bf16)v[j];
    *(bf16x4*)(Wih0b + c * 4) = o;
  } else if (c < 786432 + 131072) {
    long i = c - 786432;
    h0b[i] = (__bf16)G[i];
  } else if (c < 786432 + 262144) {
    long i = c - 786432 - 131072;
    h2b[i] = (__bf16)G[131072 + i];
  } else if (c < 786432 + 262144 + 2048) {
    flags[c - 786432 - 262144] = 0;
  }
}

// ------------------------- final LayerNorm (ddof=1, denom std+eps) -------------------------
__global__ void __launch_bounds__(256) ln_kernel(float* __restrict__ out,
                                                 const float* __restrict__ a2,
                                                 const float* __restrict__ b2) {
  int wv = threadIdx.x >> 6, lane = threadIdx.x & 63;
  size_t row = (size_t)blockIdx.x * 4 + wv;
  float* p = out + row * 1024;
  f32x4v v[4];
  float s = 0.f, ss = 0.f;
#pragma unroll
  for (int i = 0; i < 4; ++i) {
    v[i] = *(const f32x4v*)(p + (i * 64 + lane) * 4);
#pragma unroll
    for (int j = 0; j < 4; ++j) { s += v[i][j]; ss += v[i][j] * v[i][j]; }
  }
#pragma unroll
  for (int o = 32; o > 0; o >>= 1) { s += __shfl_xor(s, o); ss += __shfl_xor(ss, o); }
  float mean = s * (1.f / 1024.f);
  float var = (ss - 1024.f * mean * mean) * (1.f / 1023.f);
  var = fmaxf(var, 0.f);
  float inv = 1.f / (sqrtf(var) + 1e-6f);
#pragma unroll
  for (int i = 0; i < 4; ++i) {
    int c0 = (i * 64 + lane) * 4;
    f32x4v gA = *(const f32x4v*)(a2 + c0);
    f32x4v bo = *(const f32x4v*)(b2 + c0);
    f32x4v o;
#pragma unroll
    for (int j = 0; j < 4; ++j) o[j] = gA[j] * (v[i][j] - mean) * inv + bo[j];
    *(f32x4v*)(p + c0) = o;
  }
}

extern "C" void kernel_launch(void* const* d_in, const int* in_sizes, int n_in,
                              void* d_out, int out_size, void* d_ws, size_t ws_size,
                              hipStream_t stream) {
  const float* X    = (const float*)d_in[0];
  const float* G    = (const float*)d_in[1];
  // d_in[2] = L : dead (attention result discarded in reference)
  const float* Wih0 = (const float*)d_in[3];
  const float* Whh0 = (const float*)d_in[4];
  const float* Wih1 = (const float*)d_in[5];
  const float* Whh1 = (const float*)d_in[6];
  const float* Wlin = (const float*)d_in[7];
  const float* a2   = (const float*)d_in[8];
  const float* b2   = (const float*)d_in[9];
  float* out = (float*)d_out;

  char* ws = (char*)d_ws;
  size_t off = 0;
  auto take = [&](size_t n) { char* p = ws + off; off += (n + 255) & ~(size_t)255; return p; };
  __bf16* Wih0b = (__bf16*)take((size_t)3072 * 1024 * 2);
  __bf16* gi0b  = (__bf16*)take((size_t)16384 * 3072 * 2);   // 96 MB, [t][b][3H]
  __bf16* gh1b  = (__bf16*)take((size_t)128 * 3072 * 2);
  __bf16* h0b   = (__bf16*)take((size_t)BB * HH * 2);
  __bf16* h1b   = (__bf16*)take((size_t)BB * HH * 2 * 2);    // parity double buffer
  __bf16* h2b   = (__bf16*)take((size_t)BB * HH * 2);
  int*    flags = (int*)take(2048 * 4);
  if (off > ws_size) return; // workspace too small: fail loudly (output stays poisoned)

  prep3<<<4104, 256, 0, stream>>>(Wih0, G, Wih0b, h0b, h2b, flags);
  gi0_kernel<<<1536, 256, 0, stream>>>(X, Wih0b, gi0b);
  gru_persist<<<NWG, NT, 0, stream>>>(Whh0, Wih1, Whh1, Wlin, gi0b, G,
                                      h0b, h1b, h2b, gh1b, out, flags);
  ln_kernel<<<4096, 256, 0, stream>>>(out, a2, b2);
}

// Round 3
// 4074.950 us; speedup vs baseline: 2.3140x; 1.4004x over previous
//
#include <hip/hip_runtime.h>
#include <hip/hip_bf16.h>

#define BB 128
#define TT 128
#define HH 1024
#define NWG 256
#define NT 512

typedef __bf16 bf16x8 __attribute__((ext_vector_type(8)));
typedef __bf16 bf16x4 __attribute__((ext_vector_type(4)));
typedef float  f32x4v __attribute__((ext_vector_type(4)));

#define MFMA16(a,b,c) __builtin_amdgcn_mfma_f32_16x16x32_bf16(a,b,c,0,0,0)

__device__ inline float fsig(float x) {
  x = fminf(fmaxf(x, -30.f), 30.f);
  return 1.f / (1.f + __expf(-x));
}
__device__ inline float ftanh(float x) {
  x = fminf(fmaxf(x, -15.f), 15.f);
  float e = __expf(2.f * x);
  return (e - 1.f) / (e + 1.f);
}
__device__ inline float bf2f(unsigned short u) {
  union { unsigned int i; float f; } c; c.i = (unsigned int)u << 16; return c.f;
}
// UC (LLC coherent-point) 2B store for cross-WG state
__device__ inline void ucst16(__bf16* p, float v) {
  union { __bf16 b; unsigned short u; } c; c.b = (__bf16)v;
  __hip_atomic_store((unsigned short*)p, c.u, __ATOMIC_RELAXED, __HIP_MEMORY_SCOPE_AGENT);
}

// ---- DAG sync: per-role-per-half 64-slot flag arrays, ONE SLOT PER 64B LLC
// LINE (stride 16 ints). Rationale: unpadded, a role's 64 slots live in 1-2
// lines polled by ~128 waves continuously; the producer's signal store queues
// behind the poll-read stream (hot-line), inflating handoff latency to ~10us.
// Padding isolates each producer's line: signal visibility ~= raw LLC latency.
// Slot g: producer WG for columns g*16..g*16+15. Slots 0..31 = columns 0..511
// (colhalf 0), slots 32..63 = columns 512..1023 (colhalf 1).
#define SIGF(F) do { \
  __syncthreads(); \
  if (tid == 0) \
    __hip_atomic_store(&(F)[g * 16], t + 1, __ATOMIC_RELAXED, __HIP_MEMORY_SCOPE_AGENT); \
} while (0)

// full wait: all 64 slots
__device__ inline void wf1(const int* F, int tgt, int tid, int lane) {
  if (tid < 64) {
    while (__hip_atomic_load(&F[lane * 16], __ATOMIC_RELAXED, __HIP_MEMORY_SCOPE_AGENT) < tgt)
      __builtin_amdgcn_s_sleep(1);
    __builtin_amdgcn_fence(__ATOMIC_ACQUIRE, "agent");
  }
  __syncthreads();
  __builtin_amdgcn_sched_barrier(0);
}
// half wait: 32 slots of one column half
__device__ inline void whalf(const int* F, int ch, int tgt, int tid, int lane) {
  if (tid < 64) {
    const int* P = F + (ch * 32 + (lane & 31)) * 16;
    while (__hip_atomic_load(P, __ATOMIC_RELAXED, __HIP_MEMORY_SCOPE_AGENT) < tgt)
      __builtin_amdgcn_s_sleep(1);
    __builtin_amdgcn_fence(__ATOMIC_ACQUIRE, "agent");
  }
  __syncthreads();
  __builtin_amdgcn_sched_barrier(0);
}

// ---- stage one 16x1024 f32 weight strip into LDS as swizzled bf16 (32KB), NT=512 ----
__device__ inline void stage_strip(char* dst, const float* src, int rstride, int tid) {
#pragma unroll
  for (int it = 0; it < 8; ++it) {
    int i = tid + it * NT;
    int rr = i >> 8;
    int c4 = i & 255;
    f32x4v v = *(const f32x4v*)(src + (size_t)rr * rstride + c4 * 4);
    bf16x4 o;
#pragma unroll
    for (int j = 0; j < 4; ++j) o[j] = (__bf16)v[j];
    *(bf16x4*)(dst + rr * 2048 + ((c4 * 8) ^ ((rr & 7) << 4))) = o;
  }
}

// ---- stage one 16x1024 bf16 strip into LDS swizzled (32KB), 256 threads ----
__device__ inline void stage_strip_b16(char* dst, const __bf16* src, int tid) {
#pragma unroll
  for (int it = 0; it < 8; ++it) {
    int i = tid + it * 256;
    int rr = i >> 7;
    int c8 = i & 127;
    bf16x8 v = *(const bf16x8*)(src + (size_t)rr * 1024 + c8 * 8);
    *(bf16x8*)(dst + rr * 2048 + ((c8 * 16) ^ ((rr & 7) << 4))) = v;
  }
}

// ---- half-K GEMM burst: 16 K-chunks (kb0..kb0+15), forced register burst ----
template<int NS>
__device__ inline void gemm_half(const char* sm, const __bf16* __restrict__ A,
                                 int rowbase, int lane, int kb0, f32x4v (&acc)[NS]) {
  const int r = lane & 15, q = lane >> 4;
  const __bf16* Ap = A + (size_t)(rowbase + r) * 1024 + q * 8;
  bf16x8 a[16];
#pragma unroll
  for (int i = 0; i < 16; ++i) a[i] = *(const bf16x8*)(Ap + (kb0 + i) * 32);
  __builtin_amdgcn_sched_barrier(0);   // pin: all 16 loads issued before MFMAs
  __builtin_amdgcn_s_setprio(1);
#pragma unroll
  for (int i = 0; i < 16; ++i) {
    const int kb = kb0 + i;
    const int byteo = (kb * 64 + q * 16) ^ ((r & 7) << 4);
#pragma unroll
    for (int s = 0; s < NS; ++s) {
      bf16x8 b = *(const bf16x8*)(sm + s * 32768 + r * 2048 + byteo);
      acc[s] = MFMA16(a[i], b, acc[s]);
    }
  }
  __builtin_amdgcn_s_setprio(0);
}

// ---- full-K GEMM burst (32 chunks) ----
template<int NS>
__device__ inline void gemm_burst(const char* sm, const __bf16* __restrict__ A,
                                  int rowbase, int lane, f32x4v (&acc)[NS]) {
  const int r = lane & 15, q = lane >> 4;
  const __bf16* Ap = A + (size_t)(rowbase + r) * 1024 + q * 8;
  bf16x8 a[32];
#pragma unroll
  for (int kb = 0; kb < 32; ++kb) a[kb] = *(const bf16x8*)(Ap + kb * 32);
  __builtin_amdgcn_sched_barrier(0);
  __builtin_amdgcn_s_setprio(1);
#pragma unroll
  for (int kb = 0; kb < 32; ++kb) {
    const int byteo = (kb * 64 + q * 16) ^ ((r & 7) << 4);
#pragma unroll
    for (int s = 0; s < NS; ++s) {
      bf16x8 b = *(const bf16x8*)(sm + s * 32768 + r * 2048 + byteo);
      acc[s] = MFMA16(a[kb], b, acc[s]);
    }
  }
  __builtin_amdgcn_s_setprio(0);
}

// ------------------------- persistent recurrent kernel -------------------------
// XCD-affine roles: xcd = wg&7, role = xcd>>1. Two batch halves (rows 0-63, 64-127)
// pipeline through the roles phase-shifted (r0-proven structure). Chain waits
// split into column-half waits to pipeline refill with the producer tail.
// h1b parity-double-buffered.
__global__ void __launch_bounds__(NT, 2) gru_persist(
    const float* __restrict__ Whh0, const float* __restrict__ Wih1,
    const float* __restrict__ Whh1, const float* __restrict__ Wlin,
    const __bf16* __restrict__ gi0b, const float* __restrict__ G,
    __bf16* __restrict__ h0b, __bf16* __restrict__ h1b,
    __bf16* __restrict__ h2b, __bf16* __restrict__ gh1b,
    float* __restrict__ out, int* flags)
{
  __shared__ char sm[106496];
  float* h2s = (float*)(sm + 98304);          // [128][16] f32, role 2 persistent
  const int tid = threadIdx.x, wg = blockIdx.x;
  const int wv = tid >> 6, lane = tid & 63;
  const int xcd = wg & 7;
  const int role = xcd >> 1;
  const int g = ((wg >> 3) << 1) | (xcd & 1); // 0..63
  const int c0 = g * 16;
  const int r = lane & 15, q = lane >> 4;
  const bool gw = (wv < 4);                   // GEMM waves (4 x 16 rows = 64-row half)

  if (role == 0) {
    stage_strip(sm,         Whh0 + (size_t)c0 * 1024,          1024, tid);
    stage_strip(sm + 32768, Whh0 + (size_t)(1024 + c0) * 1024, 1024, tid);
    stage_strip(sm + 65536, Whh0 + (size_t)(2048 + c0) * 1024, 1024, tid);
  } else if (role == 1) {
    stage_strip(sm,         Whh1 + (size_t)c0 * 1024,          1024, tid);
    stage_strip(sm + 32768, Whh1 + (size_t)(1024 + c0) * 1024, 1024, tid);
    stage_strip(sm + 65536, Whh1 + (size_t)(2048 + c0) * 1024, 1024, tid);
  } else if (role == 2) {
    stage_strip(sm,         Wih1 + (size_t)c0 * 1024,          1024, tid);
    stage_strip(sm + 32768, Wih1 + (size_t)(1024 + c0) * 1024, 1024, tid);
    stage_strip(sm + 65536, Wih1 + (size_t)(2048 + c0) * 1024, 1024, tid);
    for (int i = tid; i < 2048; i += NT) {    // h2 f32 master <- G[1] slice (all rows)
      int row = i >> 4, cc = i & 15;
      h2s[i] = G[131072 + row * 1024 + c0 + cc];
    }
  } else {
    stage_strip(sm,         Wlin + (size_t)c0 * 2048,        2048, tid); // linL
    stage_strip(sm + 32768, Wlin + (size_t)c0 * 2048 + 1024, 2048, tid); // linR
  }
  __syncthreads();

  // flag bases: F(role, half) = flags + (role*2 + half)*1024  (64 slots x 16-int pad)
  int* F0h[2] = { flags + 0 * 1024, flags + 1 * 1024 };
  int* F1h[2] = { flags + 2 * 1024, flags + 3 * 1024 };
  int* F2h[2] = { flags + 4 * 1024, flags + 5 * 1024 };
  int* F3h[2] = { flags + 6 * 1024, flags + 7 * 1024 };

  if (role == 0) {
    for (int t = 0; t < TT; ++t) {
      __bf16* h1bP = h1b + (size_t)(t & 1) * 131072;   // parity buffer
#pragma unroll
      for (int h = 0; h < 2; ++h) {
        const int rowbase = h * 64 + wv * 16;
        // gi0 scalars: flag-independent — issue before waits to hide LLC latency
        unsigned short pgr[4], pgz[4], pgn[4];
        if (gw) {
#pragma unroll
          for (int gg = 0; gg < 4; ++gg) {
            int row = rowbase + q * 4 + gg;
            const unsigned short* gp =
                (const unsigned short*)(gi0b + ((size_t)t * 128 + row) * 3072 + c0 + r);
            pgr[gg] = gp[0]; pgz[gg] = gp[1024]; pgn[gg] = gp[2048];
          }
        }
        f32x4v acc[3];
#pragma unroll
        for (int s = 0; s < 3; ++s) { f32x4v z = {0,0,0,0}; acc[s] = z; }
        whalf(F3h[h], 0, t, tid, lane);            // h0 cols 0..511 ready
        if (gw) gemm_half<3>(sm, h0b, rowbase, lane, 0, acc);
        whalf(F3h[h], 1, t, tid, lane);            // h0 cols 512..1023 ready
        unsigned short ph[4];
        if (gw) {
#pragma unroll
          for (int gg = 0; gg < 4; ++gg) {         // scalars ride under MFMA half 2
            int row = rowbase + q * 4 + gg;
            ph[gg] = *(const unsigned short*)(h0b + (size_t)row * 1024 + c0 + r);
          }
          gemm_half<3>(sm, h0b, rowbase, lane, 16, acc);
#pragma unroll
          for (int gg = 0; gg < 4; ++gg) {
            int row = rowbase + q * 4 + gg;
            float rv = fsig(bf2f(pgr[gg]) + acc[0][gg]);
            float zv = fsig(bf2f(pgz[gg]) + acc[1][gg]);
            float nv = ftanh(bf2f(pgn[gg]) + rv * acc[2][gg]);
            ucst16(h1bP + (size_t)row * 1024 + c0 + r, (1.f - zv) * nv + zv * bf2f(ph[gg]));
          }
        }
        SIGF(F0h[h]);
      }
    }
  } else if (role == 1) {
    for (int t = 0; t < TT; ++t) {
#pragma unroll
      for (int h = 0; h < 2; ++h) {
        wf1(F2h[h], t, tid, lane);
        if (gw) {
          const int rowbase = h * 64 + wv * 16;
          f32x4v acc[3];
#pragma unroll
          for (int s = 0; s < 3; ++s) { f32x4v z = {0,0,0,0}; acc[s] = z; }
          gemm_burst<3>(sm, h2b, rowbase, lane, acc);
#pragma unroll
          for (int gg = 0; gg < 4; ++gg) {
            size_t base = (size_t)(rowbase + q * 4 + gg) * 3072 + c0 + r;
            ucst16(gh1b + base,        acc[0][gg]);
            ucst16(gh1b + base + 1024, acc[1][gg]);
            ucst16(gh1b + base + 2048, acc[2][gg]);
          }
        }
        SIGF(F1h[h]);
      }
    }
  } else if (role == 2) {
    for (int t = 0; t < TT; ++t) {
      const __bf16* h1bP = h1b + (size_t)(t & 1) * 131072;
#pragma unroll
      for (int h = 0; h < 2; ++h) {
        const int rowbase = h * 64 + wv * 16;
        // stage A: gh1 ready (parallel with role0) -> prefetch scalars early.
        wf1(F1h[h], t + 1, tid, lane);
        unsigned short hg0[4], hg1[4], hg2[4];
        if (gw) {
#pragma unroll
          for (int gg = 0; gg < 4; ++gg) {
            int row = rowbase + q * 4 + gg;
            const unsigned short* hp = (const unsigned short*)(gh1b + (size_t)row * 3072 + c0 + r);
            hg0[gg] = hp[0]; hg1[gg] = hp[1024]; hg2[gg] = hp[2048];
          }
        }
        // stage B: h1 in column halves
        f32x4v acc[3];
#pragma unroll
        for (int s = 0; s < 3; ++s) { f32x4v z = {0,0,0,0}; acc[s] = z; }
        whalf(F0h[h], 0, t + 1, tid, lane);
        if (gw) gemm_half<3>(sm, h1bP, rowbase, lane, 0, acc);
        whalf(F0h[h], 1, t + 1, tid, lane);
        if (gw) {
          gemm_half<3>(sm, h1bP, rowbase, lane, 16, acc);
#pragma unroll
          for (int gg = 0; gg < 4; ++gg) {
            int row = rowbase + q * 4 + gg;
            float rv = fsig(acc[0][gg] + bf2f(hg0[gg]));
            float zv = fsig(acc[1][gg] + bf2f(hg1[gg]));
            float nv = ftanh(acc[2][gg] + rv * bf2f(hg2[gg]));
            float hp = h2s[row * 16 + r];
            float h2 = (1.f - zv) * nv + zv * hp;
            h2s[row * 16 + r] = h2;
            ucst16(h2b + (size_t)row * 1024 + c0 + r, h2);
          }
        }
        SIGF(F2h[h]);
      }
    }
  } else {
    for (int t = 0; t < TT; ++t) {
#pragma unroll
      for (int h = 0; h < 2; ++h) {
        const int rowbase = h * 64 + wv * 16;
        wf1(F3h[h], t, tid, lane);     // own-role: h0(t-1) fully written
        f32x4v accL[1];
        { f32x4v z = {0,0,0,0}; accL[0] = z; }
        if (gw) gemm_burst<1>(sm, h0b, rowbase, lane, accL);
        // linR in column halves as h2 arrives
        f32x4v accR[1];
        { f32x4v z = {0,0,0,0}; accR[0] = z; }
        whalf(F2h[h], 0, t + 1, tid, lane);
        if (gw) gemm_half<1>(sm + 32768, h2b, rowbase, lane, 0, accR);
        whalf(F2h[h], 1, t + 1, tid, lane);
        if (gw) {
          gemm_half<1>(sm + 32768, h2b, rowbase, lane, 16, accR);
#pragma unroll
          for (int gg = 0; gg < 4; ++gg) {
            int row = rowbase + q * 4 + gg;
            float v = ftanh(accL[0][gg] + accR[0][gg]);
            ucst16(h0b + (size_t)row * 1024 + c0 + r, v);
            out[((size_t)row * 128 + t) * 1024 + c0 + r] = v;
          }
        }
        SIGF(F3h[h]);
      }
    }
  }
}

// ------------------------- gi0 precompute -> gi0b[t][b][3H] bf16 -------------------------
// Grid: 48 n-tiles x 32 mi-groups; each block stages 4 weight strips once and
// loops 4 batch tiles.
__global__ void __launch_bounds__(256) gi0_kernel(const float* __restrict__ X,
                                                  const __bf16* __restrict__ Wih0b,
                                                  __bf16* __restrict__ gi0b) {
  __shared__ char sm[131072];
  const int tid = threadIdx.x, wv = tid >> 6, lane = tid & 63;
  const int bi = blockIdx.x;
  const int n = bi % 48, mg = bi / 48;
#pragma unroll
  for (int s = 0; s < 4; ++s)
    stage_strip_b16(sm + s * 32768, Wih0b + (size_t)(n * 64 + s * 16) * 1024, tid);
  __syncthreads();
  const int r = lane & 15, q = lane >> 4;
  for (int mi = mg * 4; mi < mg * 4 + 4; ++mi) {
    f32x4v acc[4][2];
#pragma unroll
    for (int s = 0; s < 4; ++s) { f32x4v z = {0,0,0,0}; acc[s][0] = z; acc[s][1] = z; }
    const float* Ap = X + ((size_t)mi * 128 + wv * 32 + r) * 1024 + q * 8;
#pragma unroll 4
    for (int kb = 0; kb < 32; ++kb) {
      f32x4v x0a = *(const f32x4v*)(Ap + kb * 32);
      f32x4v x0b = *(const f32x4v*)(Ap + kb * 32 + 4);
      f32x4v x1a = *(const f32x4v*)(Ap + 16384 + kb * 32);
      f32x4v x1b = *(const f32x4v*)(Ap + 16384 + kb * 32 + 4);
      bf16x8 a0, a1;
#pragma unroll
      for (int j = 0; j < 4; ++j) {
        a0[j] = (__bf16)x0a[j]; a0[4 + j] = (__bf16)x0b[j];
        a1[j] = (__bf16)x1a[j]; a1[4 + j] = (__bf16)x1b[j];
      }
      const int byteo = (kb * 64 + q * 16) ^ ((r & 7) << 4);
#pragma unroll
      for (int s = 0; s < 4; ++s) {
        bf16x8 b = *(const bf16x8*)(sm + s * 32768 + r * 2048 + byteo);
        acc[s][0] = MFMA16(a0, b, acc[s][0]);
        acc[s][1] = MFMA16(a1, b, acc[s][1]);
      }
    }
#pragma unroll
    for (int s = 0; s < 4; ++s)
#pragma unroll
      for (int mf = 0; mf < 2; ++mf)
#pragma unroll
        for (int gg = 0; gg < 4; ++gg) {
          int trow = wv * 32 + mf * 16 + q * 4 + gg;     // = t
          gi0b[((size_t)trow * 128 + mi) * 3072 + n * 64 + s * 16 + r] = (__bf16)acc[s][mf][gg];
        }
  }
}

// ------------------------- prep: Wih0->bf16, state init, flags -------------------------
__global__ void __launch_bounds__(256) prep3(const float* __restrict__ Wih0f,
                                             const float* __restrict__ G,
                                             __bf16* Wih0b,
                                             __bf16* h0b, __bf16* h2b, int* flags) {
  long c = (long)blockIdx.x * 256 + threadIdx.x;
  if (c < 786432) {
    f32x4v v = *(const f32x4v*)(Wih0f + c * 4);
    bf16x4 o;
#pragma unroll
    for (int j = 0; j < 4; ++j) o[j] = (__bf16)v[j];
    *(bf16x4*)(Wih0b + c * 4) = o;
  } else if (c < 786432 + 131072) {
    long i = c - 786432;
    h0b[i] = (__bf16)G[i];
  } else if (c < 786432 + 262144) {
    long i = c - 786432 - 131072;
    h2b[i] = (__bf16)G[131072 + i];
  } else if (c < 786432 + 262144 + 8192) {
    flags[c - 786432 - 262144] = 0;
  }
}

// ------------------------- final LayerNorm (ddof=1, denom std+eps) -------------------------
__global__ void __launch_bounds__(256) ln_kernel(float* __restrict__ out,
                                                 const float* __restrict__ a2,
                                                 const float* __restrict__ b2) {
  int wv = threadIdx.x >> 6, lane = threadIdx.x & 63;
  size_t row = (size_t)blockIdx.x * 4 + wv;
  float* p = out + row * 1024;
  f32x4v v[4];
  float s = 0.f, ss = 0.f;
#pragma unroll
  for (int i = 0; i < 4; ++i) {
    v[i] = *(const f32x4v*)(p + (i * 64 + lane) * 4);
#pragma unroll
    for (int j = 0; j < 4; ++j) { s += v[i][j]; ss += v[i][j] * v[i][j]; }
  }
#pragma unroll
  for (int o = 32; o > 0; o >>= 1) { s += __shfl_xor(s, o); ss += __shfl_xor(ss, o); }
  float mean = s * (1.f / 1024.f);
  float var = (ss - 1024.f * mean * mean) * (1.f / 1023.f);
  var = fmaxf(var, 0.f);
  float inv = 1.f / (sqrtf(var) + 1e-6f);
#pragma unroll
  for (int i = 0; i < 4; ++i) {
    int c0 = (i * 64 + lane) * 4;
    f32x4v gA = *(const f32x4v*)(a2 + c0);
    f32x4v bo = *(const f32x4v*)(b2 + c0);
    f32x4v o;
#pragma unroll
    for (int j = 0; j < 4; ++j) o[j] = gA[j] * (v[i][j] - mean) * inv + bo[j];
    *(f32x4v*)(p + c0) = o;
  }
}

extern "C" void kernel_launch(void* const* d_in, const int* in_sizes, int n_in,
                              void* d_out, int out_size, void* d_ws, size_t ws_size,
                              hipStream_t stream) {
  const float* X    = (const float*)d_in[0];
  const float* G    = (const float*)d_in[1];
  // d_in[2] = L : dead (attention result discarded in reference)
  const float* Wih0 = (const float*)d_in[3];
  const float* Whh0 = (const float*)d_in[4];
  const float* Wih1 = (const float*)d_in[5];
  const float* Whh1 = (const float*)d_in[6];
  const float* Wlin = (const float*)d_in[7];
  const float* a2   = (const float*)d_in[8];
  const float* b2   = (const float*)d_in[9];
  float* out = (float*)d_out;

  char* ws = (char*)d_ws;
  size_t off = 0;
  auto take = [&](size_t n) { char* p = ws + off; off += (n + 255) & ~(size_t)255; return p; };
  __bf16* Wih0b = (__bf16*)take((size_t)3072 * 1024 * 2);
  __bf16* gi0b  = (__bf16*)take((size_t)16384 * 3072 * 2);   // 96 MB, [t][b][3H]
  __bf16* gh1b  = (__bf16*)take((size_t)128 * 3072 * 2);
  __bf16* h0b   = (__bf16*)take((size_t)BB * HH * 2);
  __bf16* h1b   = (__bf16*)take((size_t)BB * HH * 2 * 2);    // parity double buffer
  __bf16* h2b   = (__bf16*)take((size_t)BB * HH * 2);
  int*    flags = (int*)take(8192 * 4);                      // 64-slot arrays, 64B/slot pad
  if (off > ws_size) return; // workspace too small: fail loudly (output stays poisoned)

  prep3<<<4128, 256, 0, stream>>>(Wih0, G, Wih0b, h0b, h2b, flags);
  gi0_kernel<<<1536, 256, 0, stream>>>(X, Wih0b, gi0b);
  gru_persist<<<NWG, NT, 0, stream>>>(Whh0, Wih1, Whh1, Wlin, gi0b, G,
                                      h0b, h1b, h2b, gh1b, out, flags);
  ln_kernel<<<4096, 256, 0, stream>>>(out, a2, b2);
}